// Round 5
// baseline (934.440 us; speedup 1.0000x reference)
//
#include <hip/hip_runtime.h>
#include <math.h>

// CNN_tcn, fused d-split v3 ("fit 64 VGPRs"): one block per sample (grid 256),
// 1024 threads = 2 per row a; thread (a,h) owns d in [32h, 32h+32).
// Rounds 2-4 showed the compiler pins this kernel at a 64-VGPR budget
// (attributes ignored) and spills manual rolling-window registers to scratch
// (777 MB phantom HBM traffic in r4). v3 removes ALL manual windows:
//  - Phase A/B/D conv taps: direct indexed loads of s / base3 (L1-resident,
//    reuse distance 1-2 iters).
//  - Phase B fused y2-stats taps: re-load own just-stored base2[d-4],[d-2]
//    (L2-resident, stored 2-4 iters earlier by this wave).
//  - Phase C (in-place base2->base3) is parity-split: taps d-2,d,d+2 share
//    parity, so the un-reloadable base2 window is 3 f4 = 12 regs; y3 taps
//    re-load just-stored base3 from L2.
//  - Seam rows deferred past a barrier read plain global memory; only Phase
//    C's cross-seam base2 (concurrently overwritten by partner) needs LDS
//    capture (tailA/seamHA, 2 f4 per side per row).
// Hot live set ~55 regs -> genuinely fits the 64-reg budget; every remaining
// value is rematerializable from cache, so allocator fallback is benign.
// Workspace: ONE [B][D][A] float4 buffer; all global RAW is same-thread.

#define EPS_LN 1e-5f
typedef float4 f4;

__device__ __forceinline__ float gelu_f(float v) {
    return 0.5f * v * (1.0f + erff(v * 0.70710678118654752440f));
}

// y[o] = dilated conv taps: a = base[d-2], c = base[d], e = base[d+2]
// wd layout (4,4,1,3): [o][cin][k] flat o*12 + cin*3 + k
__device__ __forceinline__ void conv4(const f4 a, const f4 c, const f4 e,
                                      const float* __restrict__ wd, float y[4]) {
#pragma unroll
    for (int o = 0; o < 4; ++o) {
        const float* wv = wd + o * 12;
        y[o] = fmaf(a.x, wv[0], fmaf(c.x, wv[1], fmaf(e.x, wv[2],
               fmaf(a.y, wv[3], fmaf(c.y, wv[4], fmaf(e.y, wv[5],
               fmaf(a.z, wv[6], fmaf(c.z, wv[7], fmaf(e.z, wv[8],
               fmaf(a.w, wv[9], fmaf(c.w, wv[10], e.w * wv[11])))))))))));
    }
}

__device__ __forceinline__ void acc_stats(const float y[4], float& s1, float& s2) {
#pragma unroll
    for (int o = 0; o < 4; ++o) { s1 += y[o]; s2 = fmaf(y[o], y[o], s2); }
}

// block-wide reduce of (a,b2) over 1024 threads (16 waves)
__device__ __forceinline__ void block_red2(float& a, float& b2, float* red,
                                           float* bc, int tid) {
#pragma unroll
    for (int off = 32; off > 0; off >>= 1) {
        a  += __shfl_down(a,  off, 64);
        b2 += __shfl_down(b2, off, 64);
    }
    if ((tid & 63) == 0) { red[tid >> 6] = a; red[16 + (tid >> 6)] = b2; }
    __syncthreads();
    if (tid == 0) {
        float x = 0.f, y = 0.f;
#pragma unroll
        for (int i = 0; i < 16; ++i) { x += red[i]; y += red[16 + i]; }
        bc[0] = x; bc[1] = y;
    }
    __syncthreads();
    a = bc[0]; b2 = bc[1];
}

// normalize y (scale r, bias c = -m*r), pointwise wp -> gelu -> g[4];
// accumulate concat-LN stats (cs1,cs2) and the 16 t16a accumulators from the
// LDS-staged c2w transpose slice for this d (16 x f4, wave-uniform broadcast).
__device__ __forceinline__ void pw_accum(const float y[4], float r, float c,
    const float* __restrict__ wp, const float* __restrict__ cw, int cwo,
    const f4* c2wTd, float& cs1, float& cs2, float* t16a, float g[4]) {
    float yn[4];
#pragma unroll
    for (int o = 0; o < 4; ++o) yn[o] = fmaf(y[o], r, c);
#pragma unroll
    for (int o = 0; o < 4; ++o) {
        float zz = fmaf(yn[0], wp[o*4+0], fmaf(yn[1], wp[o*4+1],
                   fmaf(yn[2], wp[o*4+2], yn[3] * wp[o*4+3])));
        g[o] = gelu_f(zz);
    }
#pragma unroll
    for (int o = 0; o < 4; ++o) { cs1 += g[o]; cs2 = fmaf(g[o], g[o], cs2); }
    float u[4];
#pragma unroll
    for (int co = 0; co < 4; ++co)
        u[co] = fmaf(g[0], cw[co*12+cwo+0], fmaf(g[1], cw[co*12+cwo+1],
                fmaf(g[2], cw[co*12+cwo+2], g[3] * cw[co*12+cwo+3])));
#pragma unroll
    for (int o = 0; o < 16; ++o) {
        f4 p = c2wTd[o];
        t16a[o] = fmaf(u[0], p.x, fmaf(u[1], p.y,
                  fmaf(u[2], p.z, fmaf(u[3], p.w, t16a[o]))));
    }
}

__global__ __attribute__((amdgpu_flat_work_group_size(1024, 1024),
                          amdgpu_waves_per_eu(4, 4)))
void tcn_fused(const float* __restrict__ sIn, const float* __restrict__ wIn,
               const float* __restrict__ w1d, const float* __restrict__ w1p,
               const float* __restrict__ w2d, const float* __restrict__ w2p,
               const float* __restrict__ w3d, const float* __restrict__ w3p,
               const float* __restrict__ cw,  const float* __restrict__ c2w,
               const float* __restrict__ c3w, float* __restrict__ out,
               f4* __restrict__ baseT) {
    const int b   = blockIdx.x;
    const int tid = threadIdx.x;
    const int a   = tid & 511;              // row
    const int h   = tid >> 9;               // d-half: 0 -> [0,32), 1 -> [32,64)
    const int Dlo = h << 5;

    __shared__ float red[32];
    __shared__ float bc[2];
    __shared__ float Klds[16];
    __shared__ f4 tailA[512][2];            // base2[30],[31] (written by h=0)
    __shared__ f4 seamHA[512][2];           // base2[32],[33] (written by h=1)
    __shared__ float t16p[512][17];         // h=1 partial t16a (stride 17)
    __shared__ __align__(16) float c2wT[64 * 64];   // [d][o*4+co]

    // stage c2w transposed: c2wT[d*64 + o*4 + co] = c2w[o*256 + co*64 + d]
    for (int idx = tid; idx < 4096; idx += 1024) {
        int d = idx >> 6, rem = idx & 63, o = rem >> 2, co = rem & 3;
        c2wT[idx] = c2w[o * 256 + co * 64 + d];
    }

    // K[o] = sum_{co,d} c2w[o,co,d] * (sum_{j<12} cw[co*12+j])
    if (tid < 16) {
        float k = 0.f;
        for (int co = 0; co < 4; ++co) {
            float csum = 0.f;
            for (int j = 0; j < 12; ++j) csum += cw[co * 12 + j];
            const float* p = c2w + tid * 256 + co * 64;
            float t = 0.f;
            for (int d = 0; d < 64; ++d) t += p[d];
            k = fmaf(csum, t, k);
        }
        Klds[tid] = k;
    }

    const f4* srow = (const f4*)sIn + ((size_t)b * 512 + a) * 64;  // s: [b][a][d] f4
    f4* brow = baseT + (size_t)b * (64 * 512) + a;                 // base: [b][d][a] f4
    const f4 z4 = make_float4(0.f, 0.f, 0.f, 0.f);
    const float NY = 4.f * 512.f * 64.f;                           // 131072

    auto ldS = [&](int d) -> f4 { return ((unsigned)d < 64u) ? srow[d] : z4; };
    auto bl  = [&](int d) -> f4 { return brow[(size_t)d * 512]; };

    // ---------- Phase A: stats of y1 = conv(s) ----------
    float s1 = 0.f, s2 = 0.f;
    for (int i = 0; i < 32; ++i) {
        const int d = Dlo + i;
        float y[4]; conv4(ldS(d - 2), ldS(d), ldS(d + 2), w1d, y);
        acc_stats(y, s1, s2);
    }
    block_red2(s1, s2, red, bc, tid);
    float m1 = s1 / NY;
    float r1 = rsqrtf(s2 / NY - m1 * m1 + EPS_LN);
    float c1n = -m1 * r1;

    float t16a[16];
#pragma unroll
    for (int o = 0; o < 16; ++o) t16a[o] = 0.f;
    float cs1 = 0.f, cs2 = 0.f;

    // ---------- Phase B: x1, store base2 = s+x1, FUSED y2-stats ----------
    float q1 = 0.f, q2 = 0.f;
    for (int i = 0; i < 32; ++i) {
        const int d = Dlo + i;
        f4 s0 = ldS(d);
        float y[4]; conv4(ldS(d - 2), s0, ldS(d + 2), w1d, y);
        float g[4];
        pw_accum(y, r1, c1n, w1p, cw, 0, (const f4*)c2wT + d * 16, cs1, cs2, t16a, g);
        f4 nb;
        nb.x = s0.x + g[0]; nb.y = s0.y + g[1];
        nb.z = s0.z + g[2]; nb.w = s0.w + g[3];
        brow[(size_t)d * 512] = nb;
        if (h)  { if (i < 2)   seamHA[a][i] = nb; }       // base2[32],[33]
        else    { if (i >= 30) tailA[a][i - 30] = nb; }   // base2[30],[31]
        // fused y2 row e = d-2 (taps base2[d-4], base2[d-2], base2[d]=nb)
        if (i >= 4) {
            float y2[4]; conv4(bl(d - 4), bl(d - 2), nb, w2d, y2);
            acc_stats(y2, q1, q2);
        } else if (h == 0 && i >= 2) {          // e=0,1: a-tap out of range
            float y2[4]; conv4(z4, bl(d - 2), nb, w2d, y2);
            acc_stats(y2, q1, q2);
        }
    }
    if (h) {   // rows e=62,63: e-tap zero; own rows, immediate from L2
        float y2[4];
        conv4(bl(60), bl(62), z4, w2d, y2); acc_stats(y2, q1, q2);
        conv4(bl(61), bl(63), z4, w2d, y2); acc_stats(y2, q1, q2);
    }
    __syncthreads();                 // all base2 visible
    {   // deferred seam rows of y2: h=0 -> e=30,31; h=1 -> e=32,33
        const int e0 = 30 + 2 * h;
        for (int e = e0; e < e0 + 2; ++e) {
            float y2[4]; conv4(bl(e - 2), bl(e), bl(e + 2), w2d, y2);
            acc_stats(y2, q1, q2);
        }
    }
    block_red2(q1, q2, red, bc, tid);
    float m2s = q1 / NY;
    float r2s = rsqrtf(q2 / NY - m2s * m2s + EPS_LN);
    float c2n = -m2s * r2s;

    // ---------- Phase C: x2, base3 = base2+x2 in place, FUSED y3-stats ----------
    // Parity-split: rows d = Dlo+p+2k. Window holds base2[d-2],[d] (12 regs);
    // base2[d+2] fresh-loaded before its own overwrite (own k+1). Cross-seam
    // base2 (concurrently overwritten by partner) via tailA/seamHA LDS.
    // y3 taps are just-stored base3 rows: re-load from L2.
    float q31 = 0.f, q32 = 0.f;
    for (int p = 0; p < 2; ++p) {
        f4 um2 = h ? tailA[a][p] : z4;           // base2[Dlo+p-2]
        f4 u0  = bl(Dlo + p);                    // base2[Dlo+p]
        for (int k = 0; k < 16; ++k) {
            const int d = Dlo + p + 2 * k;
            f4 up2;
            if (k < 15) up2 = bl(d + 2);         // own base2, overwritten at k+1
            else        up2 = h ? z4 : seamHA[a][p];   // base2[32]/[33]
            float y[4]; conv4(um2, u0, up2, w2d, y);
            float g[4];
            pw_accum(y, r2s, c2n, w2p, cw, 4, (const f4*)c2wT + d * 16, cs1, cs2, t16a, g);
            f4 nb;
            nb.x = u0.x + g[0]; nb.y = u0.y + g[1];
            nb.z = u0.z + g[2]; nb.w = u0.w + g[3];
            brow[(size_t)d * 512] = nb;          // base3[d]
            // fused y3 row e = d-2 (taps base3[d-4],[d-2], nb) -- same parity
            if (k >= 2) {
                float y3[4]; conv4(bl(d - 4), bl(d - 2), nb, w3d, y3);
                acc_stats(y3, q31, q32);
            } else if (h == 0 && k == 1) {       // e=0,1: a-tap zero
                float y3[4]; conv4(z4, bl(d - 2), nb, w3d, y3);
                acc_stats(y3, q31, q32);
            }
            um2 = u0; u0 = up2;
        }
    }
    if (h) {   // rows e=62,63: e-tap zero; own base3 rows, immediate
        float y3[4];
        conv4(bl(60), bl(62), z4, w3d, y3); acc_stats(y3, q31, q32);
        conv4(bl(61), bl(63), z4, w3d, y3); acc_stats(y3, q31, q32);
    }
    __syncthreads();                 // all base3 visible
    {   // deferred seam rows of y3: h=0 -> e=30,31; h=1 -> e=32,33
        const int e0 = 30 + 2 * h;
        for (int e = e0; e < e0 + 2; ++e) {
            float y3[4]; conv4(bl(e - 2), bl(e), bl(e + 2), w3d, y3);
            acc_stats(y3, q31, q32);
        }
    }
    block_red2(q31, q32, red, bc, tid);
    float m3s = q31 / NY;
    float r3s = rsqrtf(q32 / NY - m3s * m3s + EPS_LN);
    float c3n = -m3s * r3s;

    // ---------- Phase D: x3 (base3 read-only; direct 3-tap loads) ----------
    for (int i = 0; i < 32; ++i) {
        const int d = Dlo + i;
        f4 ta = (d >= 2)  ? bl(d - 2) : z4;
        f4 tc = bl(d);
        f4 te = (d <= 61) ? bl(d + 2) : z4;
        float y[4]; conv4(ta, tc, te, w3d, y);
        float g[4];
        pw_accum(y, r3s, c3n, w3p, cw, 8, (const f4*)c2wT + d * 16, cs1, cs2, t16a, g);
    }

    // ---------- combine t16a partials + concat LN stats over [12,A,D] ----------
    if (h == 1) {
#pragma unroll
        for (int o = 0; o < 16; ++o) t16p[a][o] = t16a[o];
    }
    block_red2(cs1, cs2, red, bc, tid);        // syncs also publish t16p
    const float NC = 12.f * 512.f * 64.f;      // 393216
    float mcat = cs1 / NC;
    float rcat = rsqrtf(cs2 / NC - mcat * mcat + EPS_LN);

    // t16 values for this row (h=0 threads own the tail); LN over [16, A]
    float tv[16];
    float p1 = 0.f, p2 = 0.f;
    if (h == 0) {
#pragma unroll
        for (int o = 0; o < 16; ++o) {
            float tot = t16a[o] + t16p[a][o];
            float v = rcat * (tot - mcat * Klds[o]);
            tv[o] = v; p1 += v; p2 = fmaf(v, v, p2);
        }
    }
    block_red2(p1, p2, red, bc, tid);
    const float N16 = 16.f * 512.f;            // 8192
    float m16 = p1 / N16;
    float r16 = rsqrtf(p2 / N16 - m16 * m16 + EPS_LN);

    // c3w over 17 channels (16 normalized + raw w), then LN over A
    float v = 0.f, f1 = 0.f, f2 = 0.f;
    if (h == 0) {
        v = wIn[(size_t)b * 512 + a] * c3w[16];
#pragma unroll
        for (int o = 0; o < 16; ++o) v = fmaf((tv[o] - m16) * r16, c3w[o], v);
        f1 = v; f2 = v * v;
    }
    block_red2(f1, f2, red, bc, tid);
    float mA = f1 / 512.f;
    float rA = rsqrtf(f2 / 512.f - mA * mA + EPS_LN);
    if (h == 0) out[(size_t)b * 512 + a] = (v - mA) * rA;
}

extern "C" void kernel_launch(void* const* d_in, const int* in_sizes, int n_in,
                              void* d_out, int out_size, void* d_ws, size_t ws_size,
                              hipStream_t stream) {
    const float* s   = (const float*)d_in[0];
    const float* w   = (const float*)d_in[1];
    const float* w1d = (const float*)d_in[2];
    const float* w1p = (const float*)d_in[3];
    const float* w2d = (const float*)d_in[4];
    const float* w2p = (const float*)d_in[5];
    const float* w3d = (const float*)d_in[6];
    const float* w3p = (const float*)d_in[7];
    const float* cw  = (const float*)d_in[8];
    const float* c2w = (const float*)d_in[9];
    const float* c3w = (const float*)d_in[10];
    tcn_fused<<<dim3(256), dim3(1024), 0, stream>>>(
        s, w, w1d, w1p, w2d, w2p, w3d, w3p, cw, c2w, c3w,
        (float*)d_out, (f4*)d_ws);
}

// Round 6
// 679.402 us; speedup vs baseline: 1.3754x; 1.3754x over previous
//
#include <hip/hip_runtime.h>
#include <math.h>

// CNN_tcn, fused d-split v4 ("parity windows + no array escape"):
// one block per sample (grid 256), 1024 threads = 2 per row a; thread (a,h)
// owns d in [32h, 32h+32).
// Post-mortem of r2-r5: the phantom HBM traffic tracked (a) local arrays
// passed by pointer into pw_accum (t16a[16] -> scratch, SROA defeated) and
// (b) 36 regs of 5-deep rolling windows spilling at the 64-VGPR budget.
// v4 fixes both WITHOUT cache-reloads (r5 proved those miss all caches):
//  - PW_ACCUM is a macro; t16a only ever indexed with unrolled constants
//    at kernel scope (r0-proven register-resident pattern).
//  - All phases iterate d by PARITY (d = Dlo+p+2k): taps d-2,d,d+2 share
//    parity, so windows are 3-deep (12 regs) + 2-deep produced-value chain
//    (8 regs) instead of 5-deep + 4-deep. Hot live set ~60 regs -> fits 64.
//  - Only Phase C's cross-seam base2 needs LDS capture (tailA/seamHA);
//    deferred seam rows + Phase D boundaries read post-barrier global (L2-hot).
// Workspace: ONE [B][D][A] float4 buffer, base2 -> base3 in place; all global
// RAW is same-thread; partner data via LDS or post-barrier reads only.

#define EPS_LN 1e-5f
typedef float4 f4;

__device__ __forceinline__ float gelu_f(float v) {
    return 0.5f * v * (1.0f + erff(v * 0.70710678118654752440f));
}

// y[o] = dilated conv taps: a = base[d-2], c = base[d], e = base[d+2]
// wd layout (4,4,1,3): [o][cin][k] flat o*12 + cin*3 + k
__device__ __forceinline__ void conv4(const f4 a, const f4 c, const f4 e,
                                      const float* __restrict__ wd, float y[4]) {
#pragma unroll
    for (int o = 0; o < 4; ++o) {
        const float* wv = wd + o * 12;
        y[o] = fmaf(a.x, wv[0], fmaf(c.x, wv[1], fmaf(e.x, wv[2],
               fmaf(a.y, wv[3], fmaf(c.y, wv[4], fmaf(e.y, wv[5],
               fmaf(a.z, wv[6], fmaf(c.z, wv[7], fmaf(e.z, wv[8],
               fmaf(a.w, wv[9], fmaf(c.w, wv[10], e.w * wv[11])))))))))));
    }
}

__device__ __forceinline__ void acc_stats(const float y[4], float& s1, float& s2) {
#pragma unroll
    for (int o = 0; o < 4; ++o) { s1 += y[o]; s2 = fmaf(y[o], y[o], s2); }
}

// block-wide reduce of (a,b2) over 1024 threads (16 waves)
__device__ __forceinline__ void block_red2(float& a, float& b2, float* red,
                                           float* bc, int tid) {
#pragma unroll
    for (int off = 32; off > 0; off >>= 1) {
        a  += __shfl_down(a,  off, 64);
        b2 += __shfl_down(b2, off, 64);
    }
    if ((tid & 63) == 0) { red[tid >> 6] = a; red[16 + (tid >> 6)] = b2; }
    __syncthreads();
    if (tid == 0) {
        float x = 0.f, y = 0.f;
#pragma unroll
        for (int i = 0; i < 16; ++i) { x += red[i]; y += red[16 + i]; }
        bc[0] = x; bc[1] = y;
    }
    __syncthreads();
    a = bc[0]; b2 = bc[1];
}

// Inline pointwise+accumulate. Operates on kernel-scope cs1, cs2, t16a, c2wT.
// No arrays cross a function boundary -> SROA keeps everything in registers.
#define PW_ACCUM(Y, RR, CN, WP, CWO, DD, GV) do {                            \
    float yn0 = fmaf((Y)[0], (RR), (CN));                                    \
    float yn1 = fmaf((Y)[1], (RR), (CN));                                    \
    float yn2 = fmaf((Y)[2], (RR), (CN));                                    \
    float yn3 = fmaf((Y)[3], (RR), (CN));                                    \
    _Pragma("unroll")                                                        \
    for (int _o = 0; _o < 4; ++_o) {                                         \
        float zz = fmaf(yn0, (WP)[_o*4+0], fmaf(yn1, (WP)[_o*4+1],           \
                   fmaf(yn2, (WP)[_o*4+2], yn3 * (WP)[_o*4+3])));            \
        (GV)[_o] = gelu_f(zz);                                               \
        cs1 += (GV)[_o]; cs2 = fmaf((GV)[_o], (GV)[_o], cs2);                \
    }                                                                        \
    float _u0 = fmaf((GV)[0], cw[ 0+(CWO)], fmaf((GV)[1], cw[ 1+(CWO)],      \
                fmaf((GV)[2], cw[ 2+(CWO)], (GV)[3] * cw[ 3+(CWO)])));       \
    float _u1 = fmaf((GV)[0], cw[12+(CWO)], fmaf((GV)[1], cw[13+(CWO)],      \
                fmaf((GV)[2], cw[14+(CWO)], (GV)[3] * cw[15+(CWO)])));       \
    float _u2 = fmaf((GV)[0], cw[24+(CWO)], fmaf((GV)[1], cw[25+(CWO)],      \
                fmaf((GV)[2], cw[26+(CWO)], (GV)[3] * cw[27+(CWO)])));       \
    float _u3 = fmaf((GV)[0], cw[36+(CWO)], fmaf((GV)[1], cw[37+(CWO)],      \
                fmaf((GV)[2], cw[38+(CWO)], (GV)[3] * cw[39+(CWO)])));       \
    const f4* _cp = (const f4*)c2wT + (DD) * 16;                             \
    _Pragma("unroll")                                                        \
    for (int _o = 0; _o < 16; ++_o) {                                        \
        f4 _p = _cp[_o];                                                     \
        t16a[_o] = fmaf(_u0, _p.x, fmaf(_u1, _p.y,                           \
                   fmaf(_u2, _p.z, fmaf(_u3, _p.w, t16a[_o]))));             \
    }                                                                        \
} while (0)

__global__ __attribute__((amdgpu_flat_work_group_size(1024, 1024),
                          amdgpu_waves_per_eu(4, 4)))
void tcn_fused(const float* __restrict__ sIn, const float* __restrict__ wIn,
               const float* __restrict__ w1d, const float* __restrict__ w1p,
               const float* __restrict__ w2d, const float* __restrict__ w2p,
               const float* __restrict__ w3d, const float* __restrict__ w3p,
               const float* __restrict__ cw,  const float* __restrict__ c2w,
               const float* __restrict__ c3w, float* __restrict__ out,
               f4* __restrict__ baseT) {
    const int b   = blockIdx.x;
    const int tid = threadIdx.x;
    const int a   = tid & 511;              // row
    const int h   = tid >> 9;               // d-half: 0 -> [0,32), 1 -> [32,64)
    const int Dlo = h << 5;

    __shared__ float red[32];
    __shared__ float bc[2];
    __shared__ float Klds[16];
    __shared__ f4 tailA[512][2];            // base2[30],[31] (written by h=0)
    __shared__ f4 seamHA[512][2];           // base2[32],[33] (written by h=1)
    __shared__ float t16p[512][17];         // h=1 partial t16a (stride 17)
    __shared__ __align__(16) float c2wT[64 * 64];   // [d][o*4+co]

    // stage c2w transposed: c2wT[d*64 + o*4 + co] = c2w[o*256 + co*64 + d]
    for (int idx = tid; idx < 4096; idx += 1024) {
        int d = idx >> 6, rem = idx & 63, o = rem >> 2, co = rem & 3;
        c2wT[idx] = c2w[o * 256 + co * 64 + d];
    }

    // K[o] = sum_{co,d} c2w[o,co,d] * (sum_{j<12} cw[co*12+j])
    if (tid < 16) {
        float k = 0.f;
        for (int co = 0; co < 4; ++co) {
            float csum = 0.f;
            for (int j = 0; j < 12; ++j) csum += cw[co * 12 + j];
            const float* p = c2w + tid * 256 + co * 64;
            float t = 0.f;
            for (int d = 0; d < 64; ++d) t += p[d];
            k = fmaf(csum, t, k);
        }
        Klds[tid] = k;
    }

    const f4* srow = (const f4*)sIn + ((size_t)b * 512 + a) * 64;  // s: [b][a][d] f4
    f4* brow = baseT + (size_t)b * (64 * 512) + a;                 // base: [b][d][a] f4
    const f4 z4 = make_float4(0.f, 0.f, 0.f, 0.f);
    const float NY = 4.f * 512.f * 64.f;                           // 131072

    auto ldS = [&](int d) -> f4 { return ((unsigned)d < 64u) ? srow[d] : z4; };
    auto bl  = [&](int d) -> f4 { return brow[(size_t)d * 512]; };

    // ---------- Phase A: stats of y1 = conv(s), parity order ----------
    float s1 = 0.f, s2 = 0.f;
    for (int p = 0; p < 2; ++p) {
        f4 um2 = ldS(Dlo + p - 2), u0 = ldS(Dlo + p);
        for (int k = 0; k < 16; ++k) {
            const int d = Dlo + p + 2 * k;
            f4 up2 = ldS(d + 2);
            float y[4]; conv4(um2, u0, up2, w1d, y);
            acc_stats(y, s1, s2);
            um2 = u0; u0 = up2;
        }
    }
    block_red2(s1, s2, red, bc, tid);
    float m1 = s1 / NY;
    float r1 = rsqrtf(s2 / NY - m1 * m1 + EPS_LN);
    float c1n = -m1 * r1;

    float t16a[16];
#pragma unroll
    for (int o = 0; o < 16; ++o) t16a[o] = 0.f;
    float cs1 = 0.f, cs2 = 0.f;

    // ---------- Phase B: x1, store base2 = s+x1, FUSED y2-stats ----------
    float q1 = 0.f, q2 = 0.f;
    for (int p = 0; p < 2; ++p) {
        f4 sm2 = ldS(Dlo + p - 2), s0 = ldS(Dlo + p);
        f4 pmA = z4, pmB = z4;                 // base2[d-2], base2[d-4]
        for (int k = 0; k < 16; ++k) {
            const int d = Dlo + p + 2 * k;
            f4 sp2 = ldS(d + 2);
            float y[4]; conv4(sm2, s0, sp2, w1d, y);
            float g[4];
            PW_ACCUM(y, r1, c1n, w1p, 0, d, g);
            f4 nb;
            nb.x = s0.x + g[0]; nb.y = s0.y + g[1];
            nb.z = s0.z + g[2]; nb.w = s0.w + g[3];
            brow[(size_t)d * 512] = nb;
            if (h)  { if (k == 0)  seamHA[a][p] = nb; }   // base2[32],[33]
            else    { if (k == 15) tailA[a][p]  = nb; }   // base2[30],[31]
            // fused y2 row e = d-2 (taps base2[d-4], base2[d-2], base2[d]=nb)
            if (k >= 2) {
                float y2[4]; conv4(pmB, pmA, nb, w2d, y2);
                acc_stats(y2, q1, q2);
            } else if (h == 0 && k == 1) {     // e=0,1: a-tap out of range
                float y2[4]; conv4(z4, pmA, nb, w2d, y2);
                acc_stats(y2, q1, q2);
            }
            pmB = pmA; pmA = nb;
            sm2 = s0; s0 = sp2;
        }
        if (h) {   // rows e=62 (p=0), 63 (p=1): e-tap zero; immediate
            float y2[4]; conv4(pmB, pmA, z4, w2d, y2);
            acc_stats(y2, q1, q2);
        }
    }
    __syncthreads();                 // all base2 stored & visible
    {   // deferred seam rows of y2: h=0 -> e=30,31; h=1 -> e=32,33
        const int e0 = 30 + 2 * h;
        for (int e = e0; e < e0 + 2; ++e) {
            float y2[4]; conv4(bl(e - 2), bl(e), bl(e + 2), w2d, y2);
            acc_stats(y2, q1, q2);
        }
    }
    block_red2(q1, q2, red, bc, tid);
    float m2s = q1 / NY;
    float r2s = rsqrtf(q2 / NY - m2s * m2s + EPS_LN);
    float c2n = -m2s * r2s;

    // ---------- Phase C: x2, base3 = base2+x2 in place, FUSED y3-stats ----------
    // Parity order: window holds base2[d-2],[d]; base2[d+2] loaded fresh
    // (own row, overwritten only at own k+1). Cross-seam base2 (concurrently
    // overwritten by partner) via tailA/seamHA LDS. y3-stat taps are the
    // produced base3 chain qmA/qmB (same parity). Race-free.
    float q31 = 0.f, q32 = 0.f;
    for (int p = 0; p < 2; ++p) {
        f4 um2 = h ? tailA[a][p] : z4;         // base2[Dlo+p-2]
        f4 u0  = bl(Dlo + p);                  // base2[Dlo+p]
        f4 qmA = z4, qmB = z4;                 // base3[d-2], base3[d-4]
        for (int k = 0; k < 16; ++k) {
            const int d = Dlo + p + 2 * k;
            f4 up2;
            if (k < 15) up2 = bl(d + 2);                 // own base2
            else        up2 = h ? z4 : seamHA[a][p];     // base2[32]/[33]
            float y[4]; conv4(um2, u0, up2, w2d, y);
            float g[4];
            PW_ACCUM(y, r2s, c2n, w2p, 4, d, g);
            f4 nb;
            nb.x = u0.x + g[0]; nb.y = u0.y + g[1];
            nb.z = u0.z + g[2]; nb.w = u0.w + g[3];
            brow[(size_t)d * 512] = nb;                  // base3[d]
            // fused y3 row e = d-2 (taps base3[d-4],[d-2], nb)
            if (k >= 2) {
                float y3[4]; conv4(qmB, qmA, nb, w3d, y3);
                acc_stats(y3, q31, q32);
            } else if (h == 0 && k == 1) {     // e=0,1: a-tap zero
                float y3[4]; conv4(z4, qmA, nb, w3d, y3);
                acc_stats(y3, q31, q32);
            }
            qmB = qmA; qmA = nb;
            um2 = u0; u0 = up2;
        }
        if (h) {   // rows e=62 (p=0), 63 (p=1): e-tap zero; immediate
            float y3[4]; conv4(qmB, qmA, z4, w3d, y3);
            acc_stats(y3, q31, q32);
        }
    }
    __syncthreads();                 // all base3 stored & visible
    {   // deferred seam rows of y3: h=0 -> e=30,31; h=1 -> e=32,33
        const int e0 = 30 + 2 * h;
        for (int e = e0; e < e0 + 2; ++e) {
            float y3[4]; conv4(bl(e - 2), bl(e), bl(e + 2), w3d, y3);
            acc_stats(y3, q31, q32);
        }
    }
    block_red2(q31, q32, red, bc, tid);
    float m3s = q31 / NY;
    float r3s = rsqrtf(q32 / NY - m3s * m3s + EPS_LN);
    float c3n = -m3s * r3s;

    // ---------- Phase D: x3 (base3 read-only, parity windows; post-barrier
    // cross-seam reads are race-free plain global loads) ----------
    for (int p = 0; p < 2; ++p) {
        const int d0 = Dlo + p;
        f4 um2 = (d0 >= 2) ? bl(d0 - 2) : z4;
        f4 u0  = bl(d0);
        for (int k = 0; k < 16; ++k) {
            const int d = d0 + 2 * k;
            f4 up2 = (d + 2 <= 63) ? bl(d + 2) : z4;
            float y[4]; conv4(um2, u0, up2, w3d, y);
            float g[4];
            PW_ACCUM(y, r3s, c3n, w3p, 8, d, g);
            um2 = u0; u0 = up2;
        }
    }

    // ---------- combine t16a partials + concat LN stats over [12,A,D] ----------
    if (h == 1) {
#pragma unroll
        for (int o = 0; o < 16; ++o) t16p[a][o] = t16a[o];
    }
    block_red2(cs1, cs2, red, bc, tid);        // syncs also publish t16p
    const float NC = 12.f * 512.f * 64.f;      // 393216
    float mcat = cs1 / NC;
    float rcat = rsqrtf(cs2 / NC - mcat * mcat + EPS_LN);

    // t16 values for this row (h=0 threads own the tail); LN over [16, A]
    float tv[16];
    float p1 = 0.f, p2 = 0.f;
    if (h == 0) {
#pragma unroll
        for (int o = 0; o < 16; ++o) {
            float tot = t16a[o] + t16p[a][o];
            float v = rcat * (tot - mcat * Klds[o]);
            tv[o] = v; p1 += v; p2 = fmaf(v, v, p2);
        }
    }
    block_red2(p1, p2, red, bc, tid);
    const float N16 = 16.f * 512.f;            // 8192
    float m16 = p1 / N16;
    float r16 = rsqrtf(p2 / N16 - m16 * m16 + EPS_LN);

    // c3w over 17 channels (16 normalized + raw w), then LN over A
    float v = 0.f, f1 = 0.f, f2 = 0.f;
    if (h == 0) {
        v = wIn[(size_t)b * 512 + a] * c3w[16];
#pragma unroll
        for (int o = 0; o < 16; ++o) v = fmaf((tv[o] - m16) * r16, c3w[o], v);
        f1 = v; f2 = v * v;
    }
    block_red2(f1, f2, red, bc, tid);
    float mA = f1 / 512.f;
    float rA = rsqrtf(f2 / 512.f - mA * mA + EPS_LN);
    if (h == 0) out[(size_t)b * 512 + a] = (v - mA) * rA;
}

extern "C" void kernel_launch(void* const* d_in, const int* in_sizes, int n_in,
                              void* d_out, int out_size, void* d_ws, size_t ws_size,
                              hipStream_t stream) {
    const float* s   = (const float*)d_in[0];
    const float* w   = (const float*)d_in[1];
    const float* w1d = (const float*)d_in[2];
    const float* w1p = (const float*)d_in[3];
    const float* w2d = (const float*)d_in[4];
    const float* w2p = (const float*)d_in[5];
    const float* w3d = (const float*)d_in[6];
    const float* w3p = (const float*)d_in[7];
    const float* cw  = (const float*)d_in[8];
    const float* c2w = (const float*)d_in[9];
    const float* c3w = (const float*)d_in[10];
    tcn_fused<<<dim3(256), dim3(1024), 0, stream>>>(
        s, w, w1d, w1p, w2d, w2p, w3d, w3p, cw, c2w, c3w,
        (float*)d_out, (f4*)d_ws);
}